// Round 1
// baseline (1757.141 us; speedup 1.0000x reference)
//
#include <hip/hip_runtime.h>

#define NN 50000
#define EE 800000
#define DD 128
#define CC 16

// ---------------- degree counting ----------------
__global__ void k_degcount(const int* __restrict__ src, const int* __restrict__ dst,
                           float* __restrict__ iso, float* __restrict__ isi) {
    int e = blockIdx.x * blockDim.x + threadIdx.x;
    if (e < EE) {
        atomicAdd(&iso[src[e]], 1.0f);
        atomicAdd(&isi[dst[e]], 1.0f);
    }
}

__global__ void k_degfinalize(float* __restrict__ iso, float* __restrict__ isi) {
    int i = blockIdx.x * blockDim.x + threadIdx.x;
    if (i < NN) {
        iso[i] = rsqrtf(fmaxf(iso[i], 1.0f));
        isi[i] = rsqrtf(fmaxf(isi[i], 1.0f));
    }
}

// ---------------- 128x128 GEMM, W resident in LDS ----------------
// Y[M,128] = (X[M,128] * scale[r]?) @ W[128,128] (+ bias[c]?)
// block: 256 threads. Per pass: 8 rows. thread t: row r = t>>5, cols 4*(t&31)..+3
#define GROWS 8
__global__ __launch_bounds__(256) void k_gemm128(
        const float* __restrict__ X, const float* __restrict__ W,
        const float* __restrict__ scale, const float* __restrict__ bias,
        float* __restrict__ Y, int M, int rows_per_block) {
    __shared__ float Wl[128 * 128];
    __shared__ float Xl[GROWS][128];
    const int t = threadIdx.x;

    // stage whole W (64KB): 16384 floats / 256 thr = 16 float4 each
    for (int i = t * 4; i < 128 * 128; i += 256 * 4) {
        *(float4*)&Wl[i] = *(const float4*)&W[i];
    }

    const int row0 = blockIdx.x * rows_per_block;
    const int row_end = min(row0 + rows_per_block, M);

    const int sr = t >> 5;             // staging/compute row 0..7
    const int sc = (t & 31) * 4;       // col group 0,4,...,124

    for (int rp = row0; rp < row_end; rp += GROWS) {
        __syncthreads();               // protect Xl (and first-iter W)
        {
            int gr = rp + sr;
            float4 v = make_float4(0.f, 0.f, 0.f, 0.f);
            if (gr < M) {
                v = *(const float4*)&X[(long long)gr * DD + sc];
                if (scale) {
                    float s = scale[gr];
                    v.x *= s; v.y *= s; v.z *= s; v.w *= s;
                }
            }
            *(float4*)&Xl[sr][sc] = v;
        }
        __syncthreads();

        float4 a = make_float4(0.f, 0.f, 0.f, 0.f);
#pragma unroll
        for (int k = 0; k < 128; k += 4) {
            float4 xv = *(const float4*)&Xl[sr][k];
            float4 w0 = *(const float4*)&Wl[(k + 0) * 128 + sc];
            float4 w1 = *(const float4*)&Wl[(k + 1) * 128 + sc];
            float4 w2 = *(const float4*)&Wl[(k + 2) * 128 + sc];
            float4 w3 = *(const float4*)&Wl[(k + 3) * 128 + sc];
            a.x += xv.x * w0.x + xv.y * w1.x + xv.z * w2.x + xv.w * w3.x;
            a.y += xv.x * w0.y + xv.y * w1.y + xv.z * w2.y + xv.w * w3.y;
            a.z += xv.x * w0.z + xv.y * w1.z + xv.z * w2.z + xv.w * w3.z;
            a.w += xv.x * w0.w + xv.y * w1.w + xv.z * w2.w + xv.w * w3.w;
        }
        int gr = rp + sr;
        if (gr < M) {
            if (bias) {
                a.x += bias[sc + 0]; a.y += bias[sc + 1];
                a.z += bias[sc + 2]; a.w += bias[sc + 3];
            }
            *(float4*)&Y[(long long)gr * DD + sc] = a;
        }
    }
}

// ---------------- edge scatter: agg[dst] += h[src]*ew ----------------
__global__ __launch_bounds__(256) void k_scatter(
        const float* __restrict__ H, const int* __restrict__ src,
        const int* __restrict__ dst, const float* __restrict__ ew,
        float* __restrict__ AGG) {
    int idx = blockIdx.x * blockDim.x + threadIdx.x;  // E*128 = 102.4M < 2^31
    int e = idx >> 7;
    int d = idx & 127;
    if (e < EE) {
        int s = src[e];
        int dn = dst[e];
        float v = H[(long long)s * DD + d] * ew[e];
        atomicAdd(&AGG[(long long)dn * DD + d], v);
    }
}

// ---------------- pointwise: Y = relu?(AGG*isi + b [+ RES]) ----------------
__global__ __launch_bounds__(256) void k_point(
        const float* __restrict__ AGG, const float* __restrict__ isi,
        const float* __restrict__ bias, const float* __restrict__ RES,
        float* __restrict__ Y, int add_res) {
    int i = blockIdx.x * blockDim.x + threadIdx.x;  // N*32 threads, float4 each
    if (i < NN * 32) {
        int r = i >> 5;
        int c = (i & 31) * 4;
        float s = isi[r];
        float4 a = *(const float4*)&AGG[(long long)r * DD + c];
        float4 b = *(const float4*)&bias[c];
        float4 o;
        o.x = a.x * s + b.x; o.y = a.y * s + b.y;
        o.z = a.z * s + b.z; o.w = a.w * s + b.w;
        if (add_res) {
            float4 rv = *(const float4*)&RES[(long long)r * DD + c];
            o.x += rv.x; o.y += rv.y; o.z += rv.z; o.w += rv.w;
        }
        o.x = fmaxf(o.x, 0.f); o.y = fmaxf(o.y, 0.f);
        o.z = fmaxf(o.z, 0.f); o.w = fmaxf(o.w, 0.f);
        *(float4*)&Y[(long long)r * DD + c] = o;
    }
}

// ---------------- final projection: out[M,16] = X[M,128] @ Wo[128,16] + bo ----------------
__global__ __launch_bounds__(256) void k_gemm_out(
        const float* __restrict__ X, const float* __restrict__ Wo,
        const float* __restrict__ bo, float* __restrict__ Y, int M) {
    __shared__ float Wl[128 * 16];
    int t = threadIdx.x;
    for (int i = t * 4; i < 128 * 16; i += 256 * 4) {
        *(float4*)&Wl[i] = *(const float4*)&Wo[i];
    }
    __syncthreads();
    int r = blockIdx.x * blockDim.x + t;
    if (r < M) {
        float acc[16];
#pragma unroll
        for (int j = 0; j < 16; ++j) acc[j] = bo[j];
#pragma unroll
        for (int k = 0; k < 128; k += 4) {
            float4 x = *(const float4*)&X[(long long)r * DD + k];
#pragma unroll
            for (int j = 0; j < 16; ++j) {
                acc[j] += x.x * Wl[(k + 0) * 16 + j] + x.y * Wl[(k + 1) * 16 + j]
                        + x.z * Wl[(k + 2) * 16 + j] + x.w * Wl[(k + 3) * 16 + j];
            }
        }
#pragma unroll
        for (int j = 0; j < 16; j += 4) {
            float4 o = make_float4(acc[j], acc[j + 1], acc[j + 2], acc[j + 3]);
            *(float4*)&Y[(long long)r * CC + j] = o;
        }
    }
}

extern "C" void kernel_launch(void* const* d_in, const int* in_sizes, int n_in,
                              void* d_out, int out_size, void* d_ws, size_t ws_size,
                              hipStream_t stream) {
    const int*   src = (const int*)d_in[0];
    const int*   dst = (const int*)d_in[1];
    const float* inputs = (const float*)d_in[2];
    const float* ew  = (const float*)d_in[3];
    const float* W1  = (const float*)d_in[4];
    const float* b1  = (const float*)d_in[5];
    const float* W2  = (const float*)d_in[6];
    const float* b2  = (const float*)d_in[7];
    const float* W3  = (const float*)d_in[8];
    const float* b3  = (const float*)d_in[9];
    const float* W4  = (const float*)d_in[10];
    const float* b4  = (const float*)d_in[11];
    const float* Wr  = (const float*)d_in[12];
    const float* br  = (const float*)d_in[13];
    const float* Wo  = (const float*)d_in[14];
    const float* bo  = (const float*)d_in[15];
    float* out = (float*)d_out;

    // workspace layout
    float* iso = (float*)d_ws;            // N
    float* isi = iso + NN;                // N
    float* RES = isi + NN;                // N*128
    float* X0  = RES + (long long)NN * DD;
    float* X1  = X0  + (long long)NN * DD;
    float* AGG = X1  + (long long)NN * DD;

    const int GEMM_GRID = 512;
    const int RPB = (NN + GEMM_GRID - 1) / GEMM_GRID;  // 98

    // degrees
    hipMemsetAsync(iso, 0, sizeof(float) * NN * 2, stream);
    k_degcount<<<(EE + 255) / 256, 256, 0, stream>>>(src, dst, iso, isi);
    k_degfinalize<<<(NN + 255) / 256, 256, 0, stream>>>(iso, isi);

    // res = inputs @ Wr + br
    k_gemm128<<<GEMM_GRID, 256, 0, stream>>>(inputs, Wr, nullptr, br, RES, NN, RPB);

    const float* Ws[4]  = {W1, W2, W3, W4};
    const float* bs[4]  = {b1, b2, b3, b4};
    const float* xin = inputs;
    for (int l = 0; l < 4; ++l) {
        // h = (x * iso) @ Wl      -> X1
        k_gemm128<<<GEMM_GRID, 256, 0, stream>>>(xin, Ws[l], iso, nullptr, X1, NN, RPB);
        // agg = scatter-add
        hipMemsetAsync(AGG, 0, sizeof(float) * (long long)NN * DD, stream);
        k_scatter<<<(EE * 128) / 256, 256, 0, stream>>>(X1, src, dst, ew, AGG);
        // pointwise
        int add_res = (l == 3) ? 1 : 0;
        k_point<<<(NN * 32 + 255) / 256, 256, 0, stream>>>(AGG, isi, bs[l], RES, X0, add_res);
        xin = X0;
    }

    // out = X0 @ Wo + bo
    k_gemm_out<<<(NN + 255) / 256, 256, 0, stream>>>(X0, Wo, bo, out, NN);
}

// Round 2
// 682.720 us; speedup vs baseline: 2.5737x; 2.5737x over previous
//
#include <hip/hip_runtime.h>

#define NN 50000
#define EE 800000
#define DD 128
#define CC 16

// ---------------- degree counting (int) ----------------
__global__ void k_degcount(const int* __restrict__ src, const int* __restrict__ dst,
                           int* __restrict__ cs, int* __restrict__ cd) {
    int e = blockIdx.x * blockDim.x + threadIdx.x;
    if (e < EE) {
        atomicAdd(&cs[src[e]], 1);
        atomicAdd(&cd[dst[e]], 1);
    }
}

__global__ void k_degfinalize(const int* __restrict__ cs, const int* __restrict__ cd,
                              float* __restrict__ iso, float* __restrict__ isi) {
    int i = blockIdx.x * blockDim.x + threadIdx.x;
    if (i < NN) {
        iso[i] = rsqrtf(fmaxf((float)cs[i], 1.0f));
        isi[i] = rsqrtf(fmaxf((float)cd[i], 1.0f));
    }
}

// ---------------- exclusive scan of cd -> rowptr (single block) ----------------
#define SCAN_T 1024
#define SCAN_CHUNK ((NN + SCAN_T - 1) / SCAN_T)   // 49
__global__ __launch_bounds__(SCAN_T) void k_scan(const int* __restrict__ cnt,
                                                 int* __restrict__ rowptr) {
    __shared__ int sums[SCAN_T];
    int t = threadIdx.x;
    int i0 = t * SCAN_CHUNK;
    int i1 = min(i0 + SCAN_CHUNK, NN);
    int s = 0;
    for (int i = i0; i < i1; ++i) s += cnt[i];
    sums[t] = s;
    __syncthreads();
    for (int off = 1; off < SCAN_T; off <<= 1) {
        int v = (t >= off) ? sums[t - off] : 0;
        __syncthreads();
        sums[t] += v;
        __syncthreads();
    }
    int base = (t == 0) ? 0 : sums[t - 1];
    for (int i = i0; i < i1; ++i) { rowptr[i] = base; base += cnt[i]; }
    if (t == SCAN_T - 1) rowptr[NN] = base;
}

// ---------------- CSR fill with folded edge weight ----------------
__global__ void k_fill(const int* __restrict__ src, const int* __restrict__ dst,
                       const float* __restrict__ ew, const float* __restrict__ iso,
                       const float* __restrict__ isi, const int* __restrict__ rowptr,
                       int* __restrict__ cursor, int2* __restrict__ pairs) {
    int e = blockIdx.x * blockDim.x + threadIdx.x;
    if (e < EE) {
        int d = dst[e];
        int s = src[e];
        int pos = atomicAdd(&cursor[d], 1);
        float w = ew[e] * iso[s] * isi[d];
        int2 p;
        p.x = s;
        p.y = __float_as_int(w);
        pairs[rowptr[d] + pos] = p;
    }
}

// ---------------- CSR gather: G[n] = sum_j w_j * X[col_j]  (1 wave / node) ----------------
__global__ __launch_bounds__(256) void k_gather(
        const float* __restrict__ X, const int* __restrict__ rowptr,
        const int2* __restrict__ pairs, float* __restrict__ G) {
    int node = blockIdx.x * 4 + (threadIdx.x >> 6);
    if (node >= NN) return;
    int lane = threadIdx.x & 63;
    int c = lane * 2;
    int j = rowptr[node];
    int end = rowptr[node + 1];
    float2 acc = make_float2(0.f, 0.f);
    for (; j + 1 < end; j += 2) {
        int2 p0 = pairs[j];
        int2 p1 = pairs[j + 1];
        float w0 = __int_as_float(p0.y);
        float w1 = __int_as_float(p1.y);
        float2 h0 = *(const float2*)&X[p0.x * DD + c];
        float2 h1 = *(const float2*)&X[p1.x * DD + c];
        acc.x = fmaf(h0.x, w0, acc.x);
        acc.y = fmaf(h0.y, w0, acc.y);
        acc.x = fmaf(h1.x, w1, acc.x);
        acc.y = fmaf(h1.y, w1, acc.y);
    }
    if (j < end) {
        int2 p0 = pairs[j];
        float w0 = __int_as_float(p0.y);
        float2 h0 = *(const float2*)&X[p0.x * DD + c];
        acc.x = fmaf(h0.x, w0, acc.x);
        acc.y = fmaf(h0.y, w0, acc.y);
    }
    *(float2*)&G[node * DD + c] = acc;
}

// ---------------- 128x128 GEMM, W resident in LDS, fused epilogue ----------------
// Y[M,128] = X[M,128] @ W[128,128] + bias (+RES) (relu?)
#define GROWS 8
__global__ __launch_bounds__(256) void k_gemm128(
        const float* __restrict__ X, const float* __restrict__ W,
        const float* __restrict__ bias, const float* __restrict__ RES,
        float* __restrict__ Y, int M, int rows_per_block, int relu) {
    __shared__ float Wl[128 * 128];
    __shared__ float Xl[GROWS][128];
    const int t = threadIdx.x;

    for (int i = t * 4; i < 128 * 128; i += 256 * 4) {
        *(float4*)&Wl[i] = *(const float4*)&W[i];
    }

    const int row0 = blockIdx.x * rows_per_block;
    const int row_end = min(row0 + rows_per_block, M);

    const int sr = t >> 5;
    const int sc = (t & 31) * 4;

    for (int rp = row0; rp < row_end; rp += GROWS) {
        __syncthreads();
        {
            int gr = rp + sr;
            float4 v = make_float4(0.f, 0.f, 0.f, 0.f);
            if (gr < M) v = *(const float4*)&X[(long long)gr * DD + sc];
            *(float4*)&Xl[sr][sc] = v;
        }
        __syncthreads();

        float4 a = make_float4(0.f, 0.f, 0.f, 0.f);
#pragma unroll
        for (int k = 0; k < 128; k += 4) {
            float4 xv = *(const float4*)&Xl[sr][k];
            float4 w0 = *(const float4*)&Wl[(k + 0) * 128 + sc];
            float4 w1 = *(const float4*)&Wl[(k + 1) * 128 + sc];
            float4 w2 = *(const float4*)&Wl[(k + 2) * 128 + sc];
            float4 w3 = *(const float4*)&Wl[(k + 3) * 128 + sc];
            a.x += xv.x * w0.x + xv.y * w1.x + xv.z * w2.x + xv.w * w3.x;
            a.y += xv.x * w0.y + xv.y * w1.y + xv.z * w2.y + xv.w * w3.y;
            a.z += xv.x * w0.z + xv.y * w1.z + xv.z * w2.z + xv.w * w3.z;
            a.w += xv.x * w0.w + xv.y * w1.w + xv.z * w2.w + xv.w * w3.w;
        }
        int gr = rp + sr;
        if (gr < M) {
            a.x += bias[sc + 0]; a.y += bias[sc + 1];
            a.z += bias[sc + 2]; a.w += bias[sc + 3];
            if (RES) {
                float4 rv = *(const float4*)&RES[(long long)gr * DD + sc];
                a.x += rv.x; a.y += rv.y; a.z += rv.z; a.w += rv.w;
            }
            if (relu) {
                a.x = fmaxf(a.x, 0.f); a.y = fmaxf(a.y, 0.f);
                a.z = fmaxf(a.z, 0.f); a.w = fmaxf(a.w, 0.f);
            }
            *(float4*)&Y[(long long)gr * DD + sc] = a;
        }
    }
}

// ---------------- final projection: out[M,16] = X[M,128] @ Wo[128,16] + bo ----------------
__global__ __launch_bounds__(256) void k_gemm_out(
        const float* __restrict__ X, const float* __restrict__ Wo,
        const float* __restrict__ bo, float* __restrict__ Y, int M) {
    __shared__ float Wl[128 * 16];
    int t = threadIdx.x;
    for (int i = t * 4; i < 128 * 16; i += 256 * 4) {
        *(float4*)&Wl[i] = *(const float4*)&Wo[i];
    }
    __syncthreads();
    int r = blockIdx.x * blockDim.x + t;
    if (r < M) {
        float acc[16];
#pragma unroll
        for (int j = 0; j < 16; ++j) acc[j] = bo[j];
#pragma unroll
        for (int k = 0; k < 128; k += 4) {
            float4 x = *(const float4*)&X[(long long)r * DD + k];
#pragma unroll
            for (int j = 0; j < 16; ++j) {
                acc[j] += x.x * Wl[(k + 0) * 16 + j] + x.y * Wl[(k + 1) * 16 + j]
                        + x.z * Wl[(k + 2) * 16 + j] + x.w * Wl[(k + 3) * 16 + j];
            }
        }
#pragma unroll
        for (int j = 0; j < 16; j += 4) {
            float4 o = make_float4(acc[j], acc[j + 1], acc[j + 2], acc[j + 3]);
            *(float4*)&Y[(long long)r * CC + j] = o;
        }
    }
}

extern "C" void kernel_launch(void* const* d_in, const int* in_sizes, int n_in,
                              void* d_out, int out_size, void* d_ws, size_t ws_size,
                              hipStream_t stream) {
    const int*   src = (const int*)d_in[0];
    const int*   dst = (const int*)d_in[1];
    const float* inputs = (const float*)d_in[2];
    const float* ew  = (const float*)d_in[3];
    const float* W1  = (const float*)d_in[4];
    const float* b1  = (const float*)d_in[5];
    const float* W2  = (const float*)d_in[6];
    const float* b2  = (const float*)d_in[7];
    const float* W3  = (const float*)d_in[8];
    const float* b3  = (const float*)d_in[9];
    const float* W4  = (const float*)d_in[10];
    const float* b4  = (const float*)d_in[11];
    const float* Wr  = (const float*)d_in[12];
    const float* br  = (const float*)d_in[13];
    const float* Wo  = (const float*)d_in[14];
    const float* bo  = (const float*)d_in[15];
    float* out = (float*)d_out;

    // workspace layout
    char* p = (char*)d_ws;
    float* iso    = (float*)p; p += sizeof(float) * NN;
    float* isi    = (float*)p; p += sizeof(float) * NN;
    int*   cs     = (int*)p;   p += sizeof(int) * NN;
    int*   cd     = (int*)p;   p += sizeof(int) * NN;
    int*   cursor = (int*)p;   p += sizeof(int) * NN;
    int*   rowptr = (int*)p;   p += sizeof(int) * (NN + 1);
    p = (char*)(((uintptr_t)p + 255) & ~(uintptr_t)255);
    int2*  pairs  = (int2*)p;  p += sizeof(int2) * EE;
    float* RES    = (float*)p; p += sizeof(float) * (size_t)NN * DD;
    float* G      = (float*)p; p += sizeof(float) * (size_t)NN * DD;
    float* X0     = (float*)p; p += sizeof(float) * (size_t)NN * DD;

    const int GEMM_GRID = 512;
    const int RPB = (NN + GEMM_GRID - 1) / GEMM_GRID;  // 98

    // ---- CSR build with folded weights ----
    hipMemsetAsync(cs, 0, sizeof(int) * NN * 3, stream);   // cs, cd, cursor contiguous
    k_degcount<<<(EE + 255) / 256, 256, 0, stream>>>(src, dst, cs, cd);
    k_degfinalize<<<(NN + 255) / 256, 256, 0, stream>>>(cs, cd, iso, isi);
    k_scan<<<1, SCAN_T, 0, stream>>>(cd, rowptr);
    k_fill<<<(EE + 255) / 256, 256, 0, stream>>>(src, dst, ew, iso, isi, rowptr, cursor, pairs);

    // ---- res = inputs @ Wr + br ----
    k_gemm128<<<GEMM_GRID, 256, 0, stream>>>(inputs, Wr, br, nullptr, RES, NN, RPB, 0);

    const float* Ws[4] = {W1, W2, W3, W4};
    const float* bs[4] = {b1, b2, b3, b4};
    const float* xin = inputs;
    for (int l = 0; l < 4; ++l) {
        k_gather<<<(NN + 3) / 4, 256, 0, stream>>>(xin, rowptr, pairs, G);
        const float* res_p = (l == 3) ? RES : nullptr;
        k_gemm128<<<GEMM_GRID, 256, 0, stream>>>(G, Ws[l], bs[l], res_p, X0, NN, RPB, 1);
        xin = X0;
    }

    k_gemm_out<<<(NN + 255) / 256, 256, 0, stream>>>(X0, Wo, bo, out, NN);
}

// Round 6
// 612.750 us; speedup vs baseline: 2.8676x; 1.1142x over previous
//
#include <hip/hip_runtime.h>

#define NN 50000
#define EE 800000
#define DD 128
#define CC 16

// ---------------- degree counting (int) ----------------
__global__ void k_degcount(const int* __restrict__ src, const int* __restrict__ dst,
                           int* __restrict__ cs, int* __restrict__ cd) {
    int e = blockIdx.x * blockDim.x + threadIdx.x;
    if (e < EE) {
        atomicAdd(&cs[src[e]], 1);
        atomicAdd(&cd[dst[e]], 1);
    }
}

__global__ void k_degfinalize(const int* __restrict__ cs, const int* __restrict__ cd,
                              float* __restrict__ iso, float* __restrict__ isi) {
    int i = blockIdx.x * blockDim.x + threadIdx.x;
    if (i < NN) {
        iso[i] = rsqrtf(fmaxf((float)cs[i], 1.0f));
        isi[i] = rsqrtf(fmaxf((float)cd[i], 1.0f));
    }
}

// ---------------- hierarchical exclusive scan: cd -> rowptr ----------------
#define SBLK 256
#define NBLK_SCAN ((NN + SBLK - 1) / SBLK)   // 196

__global__ __launch_bounds__(SBLK) void k_blocksum(const int* __restrict__ cnt,
                                                   int* __restrict__ partial) {
    __shared__ int s[SBLK];
    int t = threadIdx.x;
    int i = blockIdx.x * SBLK + t;
    int v = (i < NN) ? cnt[i] : 0;
    s[t] = v;
    __syncthreads();
    for (int off = SBLK / 2; off > 0; off >>= 1) {
        if (t < off) s[t] += s[t + off];
        __syncthreads();
    }
    if (t == 0) partial[blockIdx.x] = s[0];
}

__global__ __launch_bounds__(SBLK) void k_scanpartial(const int* __restrict__ partial,
                                                      int* __restrict__ pp,
                                                      int* __restrict__ rowptr) {
    __shared__ int s[SBLK];
    int t = threadIdx.x;
    int v = (t < NBLK_SCAN) ? partial[t] : 0;
    s[t] = v;
    __syncthreads();
    for (int off = 1; off < SBLK; off <<= 1) {
        int x = (t >= off) ? s[t - off] : 0;
        __syncthreads();
        s[t] += x;
        __syncthreads();
    }
    if (t < NBLK_SCAN) pp[t] = s[t] - v;   // exclusive prefix of block partials
    if (t == SBLK - 1) rowptr[NN] = s[t];  // grand total (== EE)
}

__global__ __launch_bounds__(SBLK) void k_writerowptr(const int* __restrict__ cnt,
                                                      const int* __restrict__ pp,
                                                      int* __restrict__ rowptr) {
    __shared__ int s[SBLK];
    int t = threadIdx.x;
    int i = blockIdx.x * SBLK + t;
    int v = (i < NN) ? cnt[i] : 0;
    s[t] = v;
    __syncthreads();
    for (int off = 1; off < SBLK; off <<= 1) {
        int x = (t >= off) ? s[t - off] : 0;
        __syncthreads();
        s[t] += x;
        __syncthreads();
    }
    if (i < NN) rowptr[i] = pp[blockIdx.x] + s[t] - v;
}

// ---------------- CSR fill with folded edge weight (guarded store) ----------------
__global__ void k_fill(const int* __restrict__ src, const int* __restrict__ dst,
                       const float* __restrict__ ew, const float* __restrict__ iso,
                       const float* __restrict__ isi, const int* __restrict__ rowptr,
                       int* __restrict__ cursor, int2* __restrict__ pairs) {
    int e = blockIdx.x * blockDim.x + threadIdx.x;
    if (e < EE) {
        int d = dst[e];
        int s = src[e];
        int pos = atomicAdd(&cursor[d], 1);
        float w = ew[e] * iso[s] * isi[d];
        int2 p;
        p.x = s;
        p.y = __float_as_int(w);
        int idx = rowptr[d] + pos;
        if ((unsigned)idx < EE) pairs[idx] = p;   // defensive: never store wild
    }
}

// ---------------- CSR gather (round-2 version + defensive clamps) ----------------
// 1 wave / node, float2 per lane; 2 edges per iteration.
__global__ __launch_bounds__(256) void k_gather(
        const float* __restrict__ X, const int* __restrict__ rowptr,
        const int2* __restrict__ pairs, float* __restrict__ G) {
    int node = blockIdx.x * 4 + (threadIdx.x >> 6);
    if (node >= NN) return;
    int lane = threadIdx.x & 63;
    int c = lane * 2;
    int j = rowptr[node];
    int end = rowptr[node + 1];
    // defensive clamps: these values come from workspace memory
    j = max(0, min(j, EE));
    end = max(j, min(end, EE));
    float2 acc = make_float2(0.f, 0.f);
    for (; j + 1 < end; j += 2) {
        int2 p0 = pairs[j];
        int2 p1 = pairs[j + 1];
        int c0 = ((unsigned)p0.x < NN) ? p0.x : 0;
        int c1 = ((unsigned)p1.x < NN) ? p1.x : 0;
        float w0 = __int_as_float(p0.y);
        float w1 = __int_as_float(p1.y);
        float2 h0 = *(const float2*)&X[c0 * DD + c];
        float2 h1 = *(const float2*)&X[c1 * DD + c];
        acc.x = fmaf(h0.x, w0, acc.x);
        acc.y = fmaf(h0.y, w0, acc.y);
        acc.x = fmaf(h1.x, w1, acc.x);
        acc.y = fmaf(h1.y, w1, acc.y);
    }
    if (j < end) {
        int2 p0 = pairs[j];
        int c0 = ((unsigned)p0.x < NN) ? p0.x : 0;
        float w0 = __int_as_float(p0.y);
        float2 h0 = *(const float2*)&X[c0 * DD + c];
        acc.x = fmaf(h0.x, w0, acc.x);
        acc.y = fmaf(h0.y, w0, acc.y);
    }
    *(float2*)&G[node * DD + c] = acc;
}

// ---------------- 128x128 GEMM (round-2 version: GROWS=8), fused epilogue ----------------
// Y[M,128] = X[M,128] @ W[128,128] + bias (+RES) (relu?)
#define GROWS 8
__global__ __launch_bounds__(256) void k_gemm128(
        const float* __restrict__ X, const float* __restrict__ W,
        const float* __restrict__ bias, const float* __restrict__ RES,
        float* __restrict__ Y, int M, int rows_per_block, int relu) {
    __shared__ float Wl[128 * 128];
    __shared__ float Xl[GROWS][128];
    const int t = threadIdx.x;

    for (int i = t * 4; i < 128 * 128; i += 256 * 4) {
        *(float4*)&Wl[i] = *(const float4*)&W[i];
    }

    const int row0 = blockIdx.x * rows_per_block;
    const int row_end = min(row0 + rows_per_block, M);

    const int sr = t >> 5;
    const int sc = (t & 31) * 4;

    for (int rp = row0; rp < row_end; rp += GROWS) {
        __syncthreads();
        {
            int gr = rp + sr;
            float4 v = make_float4(0.f, 0.f, 0.f, 0.f);
            if (gr < M) v = *(const float4*)&X[(long long)gr * DD + sc];
            *(float4*)&Xl[sr][sc] = v;
        }
        __syncthreads();

        float4 a = make_float4(0.f, 0.f, 0.f, 0.f);
#pragma unroll
        for (int k = 0; k < 128; k += 4) {
            float4 xv = *(const float4*)&Xl[sr][k];
            float4 w0 = *(const float4*)&Wl[(k + 0) * 128 + sc];
            float4 w1 = *(const float4*)&Wl[(k + 1) * 128 + sc];
            float4 w2 = *(const float4*)&Wl[(k + 2) * 128 + sc];
            float4 w3 = *(const float4*)&Wl[(k + 3) * 128 + sc];
            a.x += xv.x * w0.x + xv.y * w1.x + xv.z * w2.x + xv.w * w3.x;
            a.y += xv.x * w0.y + xv.y * w1.y + xv.z * w2.y + xv.w * w3.y;
            a.z += xv.x * w0.z + xv.y * w1.z + xv.z * w2.z + xv.w * w3.z;
            a.w += xv.x * w0.w + xv.y * w1.w + xv.z * w2.w + xv.w * w3.w;
        }
        int gr = rp + sr;
        if (gr < M) {
            a.x += bias[sc + 0]; a.y += bias[sc + 1];
            a.z += bias[sc + 2]; a.w += bias[sc + 3];
            if (RES) {
                float4 rv = *(const float4*)&RES[(long long)gr * DD + sc];
                a.x += rv.x; a.y += rv.y; a.z += rv.z; a.w += rv.w;
            }
            if (relu) {
                a.x = fmaxf(a.x, 0.f); a.y = fmaxf(a.y, 0.f);
                a.z = fmaxf(a.z, 0.f); a.w = fmaxf(a.w, 0.f);
            }
            *(float4*)&Y[(long long)gr * DD + sc] = a;
        }
    }
}

// ---------------- final projection: out[M,16] = X[M,128] @ Wo[128,16] + bo ----------------
__global__ __launch_bounds__(256) void k_gemm_out(
        const float* __restrict__ X, const float* __restrict__ Wo,
        const float* __restrict__ bo, float* __restrict__ Y, int M) {
    __shared__ float Wl[128 * 16];
    int t = threadIdx.x;
    for (int i = t * 4; i < 128 * 16; i += 256 * 4) {
        *(float4*)&Wl[i] = *(const float4*)&Wo[i];
    }
    __syncthreads();
    int r = blockIdx.x * blockDim.x + t;
    if (r < M) {
        float acc[16];
#pragma unroll
        for (int j = 0; j < 16; ++j) acc[j] = bo[j];
#pragma unroll
        for (int k = 0; k < 128; k += 4) {
            float4 x = *(const float4*)&X[(long long)r * DD + k];
#pragma unroll
            for (int j = 0; j < 16; ++j) {
                acc[j] += x.x * Wl[(k + 0) * 16 + j] + x.y * Wl[(k + 1) * 16 + j]
                        + x.z * Wl[(k + 2) * 16 + j] + x.w * Wl[(k + 3) * 16 + j];
            }
        }
#pragma unroll
        for (int j = 0; j < 16; j += 4) {
            float4 o = make_float4(acc[j], acc[j + 1], acc[j + 2], acc[j + 3]);
            *(float4*)&Y[(long long)r * CC + j] = o;
        }
    }
}

extern "C" void kernel_launch(void* const* d_in, const int* in_sizes, int n_in,
                              void* d_out, int out_size, void* d_ws, size_t ws_size,
                              hipStream_t stream) {
    const int*   src = (const int*)d_in[0];
    const int*   dst = (const int*)d_in[1];
    const float* inputs = (const float*)d_in[2];
    const float* ew  = (const float*)d_in[3];
    const float* W1  = (const float*)d_in[4];
    const float* b1  = (const float*)d_in[5];
    const float* W2  = (const float*)d_in[6];
    const float* b2  = (const float*)d_in[7];
    const float* W3  = (const float*)d_in[8];
    const float* b3  = (const float*)d_in[9];
    const float* W4  = (const float*)d_in[10];
    const float* b4  = (const float*)d_in[11];
    const float* Wr  = (const float*)d_in[12];
    const float* br  = (const float*)d_in[13];
    const float* Wo  = (const float*)d_in[14];
    const float* bo  = (const float*)d_in[15];
    float* out = (float*)d_out;

    // workspace layout
    char* p = (char*)d_ws;
    float* iso    = (float*)p; p += sizeof(float) * NN;
    float* isi    = (float*)p; p += sizeof(float) * NN;
    int*   cs     = (int*)p;   p += sizeof(int) * NN;
    int*   cd     = (int*)p;   p += sizeof(int) * NN;
    int*   cursor = (int*)p;   p += sizeof(int) * NN;
    int*   rowptr = (int*)p;   p += sizeof(int) * (NN + 1);
    int*   partial= (int*)p;   p += sizeof(int) * NBLK_SCAN;
    int*   pp     = (int*)p;   p += sizeof(int) * NBLK_SCAN;
    p = (char*)(((uintptr_t)p + 255) & ~(uintptr_t)255);
    int2*  pairs  = (int2*)p;  p += sizeof(int2) * EE;
    float* RES    = (float*)p; p += sizeof(float) * (size_t)NN * DD;
    float* G      = (float*)p; p += sizeof(float) * (size_t)NN * DD;
    float* X0     = (float*)p; p += sizeof(float) * (size_t)NN * DD;

    const int GEMM_GRID = 512;
    const int RPB = (NN + GEMM_GRID - 1) / GEMM_GRID;  // 98

    // ---- CSR build with folded weights ----
    hipMemsetAsync(cs, 0, sizeof(int) * NN * 3, stream);  // cs, cd, cursor contiguous
    k_degcount<<<(EE + 255) / 256, 256, 0, stream>>>(src, dst, cs, cd);
    k_degfinalize<<<(NN + 255) / 256, 256, 0, stream>>>(cs, cd, iso, isi);
    k_blocksum<<<NBLK_SCAN, SBLK, 0, stream>>>(cd, partial);
    k_scanpartial<<<1, SBLK, 0, stream>>>(partial, pp, rowptr);
    k_writerowptr<<<NBLK_SCAN, SBLK, 0, stream>>>(cd, pp, rowptr);
    k_fill<<<(EE + 255) / 256, 256, 0, stream>>>(src, dst, ew, iso, isi, rowptr, cursor, pairs);

    // ---- res = inputs @ Wr + br ----
    k_gemm128<<<GEMM_GRID, 256, 0, stream>>>(inputs, Wr, br, nullptr, RES, NN, RPB, 0);

    const float* Ws[4] = {W1, W2, W3, W4};
    const float* bs[4] = {b1, b2, b3, b4};
    const float* xin = inputs;
    for (int l = 0; l < 4; ++l) {
        k_gather<<<(NN + 3) / 4, 256, 0, stream>>>(xin, rowptr, pairs, G);
        const float* res_p = (l == 3) ? RES : nullptr;
        k_gemm128<<<GEMM_GRID, 256, 0, stream>>>(G, Ws[l], bs[l], res_p, X0, NN, RPB, 1);
        xin = X0;
    }

    k_gemm_out<<<(NN + 255) / 256, 256, 0, stream>>>(X0, Wo, bo, out, NN);
}